// Round 1
// baseline (1521.951 us; speedup 1.0000x reference)
//
#include <hip/hip_runtime.h>

#define NPER 24
#define B_ 32
#define N_ 1024
#define F_ 128
#define H_ 64
#define E_ 16

// ---------------------------------------------------------------------------
// Kernel 1: env_emb[n,h] = relu(env_features[n,:] @ env_W[:,h] + env_b[h])
// ---------------------------------------------------------------------------
__global__ __launch_bounds__(256) void env_kernel(
    const float* __restrict__ env_features,  // [N, E]
    const float* __restrict__ env_W,         // [E, H]
    const float* __restrict__ env_b,         // [H]
    float* __restrict__ env_emb)             // [N, H]
{
    int idx = blockIdx.x * 256 + threadIdx.x;    // N_*H_ total
    int n = idx >> 6;
    int h = idx & 63;
    float acc = env_b[h];
#pragma unroll
    for (int e = 0; e < E_; ++e)
        acc = fmaf(env_features[n * E_ + e], env_W[e * H_ + h], acc);
    env_emb[idx] = fmaxf(acc, 0.f);
}

// ---------------------------------------------------------------------------
// Kernel 2: support = x @ W ; residual = relu(x @ rW + rb)
// x: [B*N, F] rows; one block handles 32 rows. 256 threads:
//   f = t & 127, row-group = t >> 7 (16 rows each).
// ---------------------------------------------------------------------------
__global__ __launch_bounds__(256) void support_residual_kernel(
    const float* __restrict__ x,        // [B*N, F]
    const float* __restrict__ W,        // [F, F]
    const float* __restrict__ rW,       // [F, F]
    const float* __restrict__ rb,       // [F]
    float* __restrict__ support,        // [B*N, F]
    float* __restrict__ residual)       // [B*N, F]
{
    __shared__ float s_in[32][F_];
    const int t = threadIdx.x;
    const size_t row0 = (size_t)blockIdx.x * 32;

    for (int i = t; i < 32 * F_; i += 256)
        s_in[i >> 7][i & 127] = x[row0 * F_ + i];
    __syncthreads();

    const int f  = t & 127;
    const int rg = t >> 7;   // 0 or 1
    float acc1[16], acc2[16];
#pragma unroll
    for (int i = 0; i < 16; ++i) { acc1[i] = 0.f; acc2[i] = 0.f; }

    for (int d = 0; d < F_; ++d) {
        float w1 = W[d * F_ + f];
        float w2 = rW[d * F_ + f];
#pragma unroll
        for (int i = 0; i < 16; ++i) {
            float xv = s_in[rg * 16 + i][d];   // wave-uniform -> LDS broadcast
            acc1[i] = fmaf(xv, w1, acc1[i]);
            acc2[i] = fmaf(xv, w2, acc2[i]);
        }
    }

    float rbf = rb[f];
#pragma unroll
    for (int i = 0; i < 16; ++i) {
        size_t row = row0 + rg * 16 + i;
        support[row * F_ + f]  = acc1[i];
        residual[row * F_ + f] = fmaxf(acc2[i] + rbf, 0.f);
    }
}

// ---------------------------------------------------------------------------
// Kernel 3: fused scores -> relu*mask -> conv -> +bias +residual -> relu
// Block = (b, n-tile of 32 rows), 256 threads.
// Loops over 32-row m-tiles: stage tgt(+env), static_adj, support in LDS,
// compute 32x32 score tile, then rank-32 update of acc[32 rows][128 f].
// Thread t: acc rows r = t>>3, f = (t&7) + 8*j  (j = 0..15)  -> conflict-free
// s_sup broadcasts.
// ---------------------------------------------------------------------------
__global__ __launch_bounds__(256) void conv_kernel(
    const float* __restrict__ src_emb,   // [P, N, H]
    const float* __restrict__ tgt_emb,   // [P, N, H]
    const float* __restrict__ env_emb,   // [N, H]
    const float* __restrict__ adj,       // [N, N] static mask
    const float* __restrict__ support,   // [B, N, F]
    const float* __restrict__ residual,  // [B, N, F]
    const float* __restrict__ bias,      // [F]
    const int* __restrict__ cyc,         // [B]
    float* __restrict__ out)             // [B, N, F]
{
    __shared__ float s_src[32][H_ + 1];   // +1 pad: kill stride-64 conflicts
    __shared__ float s_tgt[32][H_ + 1];
    __shared__ float s_adj[32][32];
    __shared__ float s_sc[32][33];
    __shared__ float s_sup[32][F_];

    const int b  = blockIdx.y;
    const int n0 = blockIdx.x * 32;
    const int t  = threadIdx.x;
    const int p  = ((cyc[b] % NPER) + NPER) % NPER;

    const size_t emb_base = (size_t)p * N_ * H_;

    // src rows for this n-tile (loaded once)
    for (int i = t; i < 32 * H_; i += 256) {
        int r = i >> 6, h = i & 63;
        s_src[r][h] = src_emb[emb_base + (size_t)(n0 + r) * H_ + h]
                    + env_emb[(n0 + r) * H_ + h];
    }

    const int r_acc = t >> 3;        // 0..31 accumulator row
    const int fl    = t & 7;         // f lane: f = fl + 8*j
    float acc[16];
#pragma unroll
    for (int j = 0; j < 16; ++j) acc[j] = 0.f;

    const int sr = t & 31;           // score row
    const int cg = t >> 5;           // score col group 0..7

    for (int mt = 0; mt < N_ / 32; ++mt) {
        const int m0 = mt * 32;
        __syncthreads();   // previous iteration done with s_tgt/s_adj/s_sup

        for (int i = t; i < 32 * H_; i += 256) {
            int r = i >> 6, h = i & 63;
            s_tgt[r][h] = tgt_emb[emb_base + (size_t)(m0 + r) * H_ + h]
                        + env_emb[(m0 + r) * H_ + h];
        }
        for (int i = t; i < 32 * 32; i += 256) {
            int r = i >> 5, c = i & 31;
            s_adj[r][c] = adj[(size_t)(n0 + r) * N_ + (m0 + c)];
        }
        for (int i = t; i < 32 * F_; i += 256) {
            int r = i >> 7, f = i & 127;
            s_sup[r][f] = support[(size_t)b * N_ * F_ + (size_t)(m0 + r) * F_ + f];
        }
        __syncthreads();

        // 32x32 score tile: each thread does 4 dot-64s
#pragma unroll
        for (int cc4 = 0; cc4 < 4; ++cc4) {
            const int cc = cg + cc4 * 8;
            float s = 0.f;
#pragma unroll
            for (int h = 0; h < H_; ++h)
                s = fmaf(s_src[sr][h], s_tgt[cc][h], s);
            s_sc[sr][cc] = s;
        }
        __syncthreads();

        // rank-32 update
#pragma unroll
        for (int mm = 0; mm < 32; ++mm) {
            float a = fmaxf(s_sc[r_acc][mm], 0.f) * s_adj[r_acc][mm];
#pragma unroll
            for (int j = 0; j < 16; ++j)
                acc[j] = fmaf(a, s_sup[mm][fl + 8 * j], acc[j]);
        }
    }

    // epilogue: out = relu(conv + bias + residual)
    const size_t base = (size_t)b * N_ * F_ + (size_t)(n0 + r_acc) * F_;
#pragma unroll
    for (int j = 0; j < 16; ++j) {
        int f = fl + 8 * j;
        float v = acc[j] + bias[f] + residual[base + f];
        out[base + f] = fmaxf(v, 0.f);
    }
}

// ---------------------------------------------------------------------------
extern "C" void kernel_launch(void* const* d_in, const int* in_sizes, int n_in,
                              void* d_out, int out_size, void* d_ws, size_t ws_size,
                              hipStream_t stream) {
    const float* input_features = (const float*)d_in[0];   // [B,N,F]
    const int*   cycle_indices  = (const int*)  d_in[1];   // [B]
    const float* weight         = (const float*)d_in[2];   // [F,F]
    const float* bias           = (const float*)d_in[3];   // [F]
    const float* src_emb        = (const float*)d_in[4];   // [P,N,H]
    const float* tgt_emb        = (const float*)d_in[5];   // [P,N,H]
    const float* env_W          = (const float*)d_in[6];   // [E,H]
    const float* env_b          = (const float*)d_in[7];   // [H]
    const float* res_W          = (const float*)d_in[8];   // [F,F]
    const float* res_b          = (const float*)d_in[9];   // [F]
    const float* static_adj     = (const float*)d_in[10];  // [N,N]
    const float* env_features   = (const float*)d_in[11];  // [N,E]
    float* out = (float*)d_out;

    // workspace layout
    float* env_emb  = (float*)d_ws;                          // N*H      = 64K floats
    float* support  = env_emb + (size_t)N_ * H_;             // B*N*F    = 4.19M floats
    float* residual = support + (size_t)B_ * N_ * F_;        // B*N*F

    env_kernel<<<(N_ * H_) / 256, 256, 0, stream>>>(
        env_features, env_W, env_b, env_emb);

    support_residual_kernel<<<(B_ * N_) / 32, 256, 0, stream>>>(
        input_features, weight, res_W, res_b, support, residual);

    dim3 grid(N_ / 32, B_);
    conv_kernel<<<grid, 256, 0, stream>>>(
        src_emb, tgt_emb, env_emb, static_adj, support, residual,
        bias, cycle_indices, out);
}

// Round 2
// 135.201 us; speedup vs baseline: 11.2570x; 11.2570x over previous
//
#include <hip/hip_runtime.h>

#define NPER 24
#define B_ 32
#define N_ 1024
#define F_ 128
#define H_ 64
#define E_ 16

typedef __attribute__((ext_vector_type(8))) short short8;
typedef __attribute__((ext_vector_type(4))) float f32x4;

static __device__ __forceinline__ unsigned short f2bf(float x) {
    union { float f; unsigned u; } v; v.f = x;
    unsigned r = v.u + 0x7fffu + ((v.u >> 16) & 1u);   // RNE
    return (unsigned short)(r >> 16);
}
static __device__ __forceinline__ float bf2f(unsigned short h) {
    union { unsigned u; float f; } v; v.u = ((unsigned)h) << 16; return v.f;
}

// ---------------------------------------------------------------------------
// K1: env_emb[n,h] = relu(env_features @ env_W + env_b)   (fp32, tiny)
// ---------------------------------------------------------------------------
__global__ __launch_bounds__(256) void env_kernel(
    const float* __restrict__ env_features,  // [N, E]
    const float* __restrict__ env_W,         // [E, H]
    const float* __restrict__ env_b,         // [H]
    float* __restrict__ env_emb)             // [N, H]
{
    int idx = blockIdx.x * 256 + threadIdx.x;
    int n = idx >> 6, h = idx & 63;
    float acc = env_b[h];
#pragma unroll
    for (int e = 0; e < E_; ++e)
        acc = fmaf(env_features[n * E_ + e], env_W[e * H_ + h], acc);
    env_emb[idx] = fmaxf(acc, 0.f);
}

// ---------------------------------------------------------------------------
// K2: src_bf/tgt_bf[p,n,h] = bf16(emb + env_emb[n,h])  for all 24 periods
// ---------------------------------------------------------------------------
__global__ __launch_bounds__(256) void srctgt_kernel(
    const float* __restrict__ src_emb, const float* __restrict__ tgt_emb,
    const float* __restrict__ env_emb,
    unsigned short* __restrict__ src_bf, unsigned short* __restrict__ tgt_bf)
{
    size_t idx = (size_t)blockIdx.x * 256 + threadIdx.x;   // < 24*65536
    float e = env_emb[idx & 65535u];
    src_bf[idx] = f2bf(src_emb[idx] + e);
    tgt_bf[idx] = f2bf(tgt_emb[idx] + e);
}

// ---------------------------------------------------------------------------
// K3: x -> bf16 (vectorized)
// ---------------------------------------------------------------------------
__global__ __launch_bounds__(256) void xcvt_kernel(
    const float* __restrict__ x, unsigned short* __restrict__ xb)
{
    size_t i = ((size_t)blockIdx.x * 256 + threadIdx.x) * 4;
    float4 v = *(const float4*)(x + i);
    ushort4 o; o.x = f2bf(v.x); o.y = f2bf(v.y); o.z = f2bf(v.z); o.w = f2bf(v.w);
    *(ushort4*)(xb + i) = o;
}

// ---------------------------------------------------------------------------
// K4: Wt[f][d] = bf16(W[d][f]);  rWt likewise  (k-contiguous B operands)
// ---------------------------------------------------------------------------
__global__ __launch_bounds__(256) void wtrans_kernel(
    const float* __restrict__ W, const float* __restrict__ rW,
    unsigned short* __restrict__ Wt, unsigned short* __restrict__ rWt)
{
    int idx = blockIdx.x * 256 + threadIdx.x;   // 0..32767
    int which = idx >> 14, j = idx & 16383;
    int f = j >> 7, d = j & 127;
    if (which == 0) Wt[f * 128 + d]  = f2bf(W[d * 128 + f]);
    else            rWt[f * 128 + d] = f2bf(rW[d * 128 + f]);
}

// ---------------------------------------------------------------------------
// K5: support^T (swapped GEMM) + residual, both bf16 out, MFMA.
// Block = 32 rows of x. Wave w: mblk = w>>1, fhalf = w&1.
// ---------------------------------------------------------------------------
__global__ __launch_bounds__(256) void gemm2_mfma(
    const unsigned short* __restrict__ x_bf,   // [B*N][128]
    const unsigned short* __restrict__ Wt,     // [128f][128d]
    const unsigned short* __restrict__ rWt,    // [128f][128d]
    const float* __restrict__ rb,              // [128]
    unsigned short* __restrict__ supT,         // [B][128f][1024m]
    unsigned short* __restrict__ resid)        // [B*N][128]
{
    const int t = threadIdx.x, w = t >> 6, l = t & 63;
    const int ln = l & 15, kb = l >> 4;
    const int mblk = w >> 1, fhalf = w & 1;
    const int row0 = blockIdx.x * 32;
    const int b   = row0 >> 10;
    const int mg0 = row0 & 1023;

    const unsigned short* xrow = x_bf + (size_t)(row0 + mblk * 16 + ln) * 128;
    short8 xa[4];
#pragma unroll
    for (int k = 0; k < 4; ++k)
        xa[k] = *(const short8*)(xrow + k * 32 + kb * 8);

    f32x4 accS[4], accR[4];
#pragma unroll
    for (int i = 0; i < 4; ++i) { accS[i] = (f32x4){0,0,0,0}; accR[i] = (f32x4){0,0,0,0}; }

#pragma unroll
    for (int k = 0; k < 4; ++k) {
#pragma unroll
        for (int fb = 0; fb < 4; ++fb) {
            int fr = (fhalf * 4 + fb) * 16 + ln;
            short8 wa = *(const short8*)(Wt  + (size_t)fr * 128 + k * 32 + kb * 8);
            short8 wb = *(const short8*)(rWt + (size_t)fr * 128 + k * 32 + kb * 8);
            accS[fb] = __builtin_amdgcn_mfma_f32_16x16x32_bf16(wa, xa[k], accS[fb], 0, 0, 0);
            accR[fb] = __builtin_amdgcn_mfma_f32_16x16x32_bf16(xa[k], wb, accR[fb], 0, 0, 0);
        }
    }

    // support^T: C[f][m], col m = ln, row f = tile*16 + kb*4 + i
#pragma unroll
    for (int fb = 0; fb < 4; ++fb) {
        int m = mg0 + mblk * 16 + ln;
#pragma unroll
        for (int i = 0; i < 4; ++i) {
            int f = (fhalf * 4 + fb) * 16 + kb * 4 + i;
            supT[((size_t)b * 128 + f) * 1024 + m] = f2bf(accS[fb][i]);
        }
    }
    // residual: C[m][f], col f = ln, row m = mblk*16 + kb*4 + i
#pragma unroll
    for (int fb = 0; fb < 4; ++fb) {
        int f = (fhalf * 4 + fb) * 16 + ln;
        float rbf = rb[f];
#pragma unroll
        for (int i = 0; i < 4; ++i) {
            size_t row = (size_t)row0 + mblk * 16 + kb * 4 + i;
            resid[row * 128 + f] = f2bf(fmaxf(accR[fb][i] + rbf, 0.f));
        }
    }
}

// ---------------------------------------------------------------------------
// K6: fused scores -> relu*adj -> conv -> +bias +residual -> relu  (MFMA)
// Block = (b, 32-row n-tile), 4 waves. Wave w: nblk = w>>1, mhalf/fhalf = w&1.
// Per 32-m tile: 2 score MFMAs (frags direct from global), mask in fp32,
// bf16 A-tile round-trip through padded LDS, 4 conv MFMAs vs support^T.
// ---------------------------------------------------------------------------
__global__ __launch_bounds__(256) void conv_mfma(
    const unsigned short* __restrict__ src_bf,  // [P][N][64]
    const unsigned short* __restrict__ tgt_bf,  // [P][N][64]
    const float* __restrict__ adj,              // [N][N]
    const unsigned short* __restrict__ supT,    // [B][128][1024]
    const unsigned short* __restrict__ resid,   // [B*N][128]
    const float* __restrict__ bias,             // [128]
    const int* __restrict__ cyc,                // [B]
    float* __restrict__ out)                    // [B][N][128]
{
    __shared__ unsigned short s_a[32 * 40] __attribute__((aligned(16)));  // [n][m], pad->40

    const int b = blockIdx.y, n0 = blockIdx.x * 32;
    const int t = threadIdx.x, w = t >> 6, l = t & 63;
    const int p = ((cyc[b] % NPER) + NPER) % NPER;
    const int ln = l & 15, kb = l >> 4;
    const int nblk = w >> 1, mhalf = w & 1;

    // hoisted src A-fragments (K = 64 -> 2 k-steps)
    const unsigned short* srow =
        src_bf + ((size_t)p * N_ + n0 + nblk * 16 + ln) * H_;
    short8 a0 = *(const short8*)(srow + kb * 8);
    short8 a1 = *(const short8*)(srow + 32 + kb * 8);

    f32x4 acc[4];
#pragma unroll
    for (int i = 0; i < 4; ++i) acc[i] = (f32x4){0, 0, 0, 0};

    const unsigned short* tbase = tgt_bf + (size_t)p * N_ * H_;
    const unsigned short* supb  = supT + (size_t)b * 128 * 1024;

    for (int m0 = 0; m0 < N_; m0 += 32) {
        // scores: tile (nblk, mblk = mhalf)
        const unsigned short* trow = tbase + (size_t)(m0 + mhalf * 16 + ln) * H_;
        short8 b0 = *(const short8*)(trow + kb * 8);
        short8 b1 = *(const short8*)(trow + 32 + kb * 8);
        f32x4 c = (f32x4){0, 0, 0, 0};
        c = __builtin_amdgcn_mfma_f32_16x16x32_bf16(a0, b0, c, 0, 0, 0);
        c = __builtin_amdgcn_mfma_f32_16x16x32_bf16(a1, b1, c, 0, 0, 0);

        // mask: A = relu(score) * adj, write bf16 tile to LDS
        const int nl = nblk * 16 + kb * 4;      // local row base (C layout)
        const int ml = mhalf * 16 + ln;         // local col
        const float* adjp = adj + (size_t)(n0 + nl) * N_ + m0 + ml;
#pragma unroll
        for (int i = 0; i < 4; ++i) {
            float a = fmaxf(c[i], 0.f) * adjp[(size_t)i * N_];
            s_a[(nl + i) * 40 + ml] = f2bf(a);
        }
        __syncthreads();

        // conv: A-frag from LDS, B-frags (support^T) direct from global
        short8 af = *(const short8*)(s_a + (nblk * 16 + ln) * 40 + kb * 8);
#pragma unroll
        for (int fb = 0; fb < 4; ++fb) {
            int f = (mhalf * 4 + fb) * 16 + ln;
            short8 bs = *(const short8*)(supb + (size_t)f * 1024 + m0 + kb * 8);
            acc[fb] = __builtin_amdgcn_mfma_f32_16x16x32_bf16(af, bs, acc[fb], 0, 0, 0);
        }
        __syncthreads();
    }

    // epilogue: out = relu(conv + bias + residual)
#pragma unroll
    for (int fb = 0; fb < 4; ++fb) {
        int f = (mhalf * 4 + fb) * 16 + ln;
        float bi = bias[f];
#pragma unroll
        for (int i = 0; i < 4; ++i) {
            int n = n0 + nblk * 16 + kb * 4 + i;
            size_t o = ((size_t)b * N_ + n) * 128 + f;
            out[o] = fmaxf(acc[fb][i] + bi + bf2f(resid[o]), 0.f);
        }
    }
}

// ---------------------------------------------------------------------------
extern "C" void kernel_launch(void* const* d_in, const int* in_sizes, int n_in,
                              void* d_out, int out_size, void* d_ws, size_t ws_size,
                              hipStream_t stream) {
    const float* input_features = (const float*)d_in[0];
    const int*   cycle_indices  = (const int*)  d_in[1];
    const float* weight         = (const float*)d_in[2];
    const float* bias           = (const float*)d_in[3];
    const float* src_emb        = (const float*)d_in[4];
    const float* tgt_emb        = (const float*)d_in[5];
    const float* env_W          = (const float*)d_in[6];
    const float* env_b          = (const float*)d_in[7];
    const float* res_W          = (const float*)d_in[8];
    const float* res_b          = (const float*)d_in[9];
    const float* static_adj     = (const float*)d_in[10];
    const float* env_features   = (const float*)d_in[11];
    float* out = (float*)d_out;

    // workspace layout (bytes, all 16B-aligned)
    char* wsb = (char*)d_ws;
    float*          env_emb = (float*)wsb;                       // 262144 B
    unsigned short* src_bf  = (unsigned short*)(wsb + 262144);   // 3145728 B
    unsigned short* tgt_bf  = src_bf + (size_t)NPER * N_ * H_;   // 3145728 B
    unsigned short* x_bf    = tgt_bf + (size_t)NPER * N_ * H_;   // 8388608 B
    unsigned short* Wt      = x_bf   + (size_t)B_ * N_ * F_;     // 32768 B
    unsigned short* rWt     = Wt     + 16384;                    // 32768 B
    unsigned short* supT    = rWt    + 16384;                    // 8388608 B
    unsigned short* resid   = supT   + (size_t)B_ * F_ * N_;     // 8388608 B
    // total ~30.3 MB

    env_kernel<<<(N_ * H_) / 256, 256, 0, stream>>>(env_features, env_W, env_b, env_emb);

    srctgt_kernel<<<(NPER * N_ * H_) / 256, 256, 0, stream>>>(
        src_emb, tgt_emb, env_emb, src_bf, tgt_bf);

    xcvt_kernel<<<(B_ * N_ * F_) / (4 * 256), 256, 0, stream>>>(input_features, x_bf);

    wtrans_kernel<<<(2 * F_ * F_) / 256, 256, 0, stream>>>(weight, res_W, Wt, rWt);

    gemm2_mfma<<<(B_ * N_) / 32, 256, 0, stream>>>(x_bf, Wt, rWt, res_b, supT, resid);

    dim3 grid(N_ / 32, B_);
    conv_mfma<<<grid, 256, 0, stream>>>(
        src_bf, tgt_bf, static_adj, supT, resid, bias, cycle_indices, out);
}

// Round 3
// 105.905 us; speedup vs baseline: 14.3709x; 1.2766x over previous
//
#include <hip/hip_runtime.h>
#include <hip/hip_bf16.h>

#define NPER 24
#define B_ 32
#define N_ 1024
#define F_ 128
#define H_ 64
#define E_ 16

typedef __attribute__((ext_vector_type(8))) short short8;
typedef __attribute__((ext_vector_type(4))) float f32x4;

static __device__ __forceinline__ unsigned short f2bf(float x) {
    union { float f; unsigned u; } v; v.f = x;
    unsigned r = v.u + 0x7fffu + ((v.u >> 16) & 1u);   // RNE
    return (unsigned short)(r >> 16);
}
static __device__ __forceinline__ float bf2f(unsigned short h) {
    union { unsigned u; float f; } v; v.u = ((unsigned)h) << 16; return v.f;
}
static __device__ __forceinline__ unsigned short f2bf_hw(float x) {
    __hip_bfloat16 h = __float2bfloat16(x);
    return *(unsigned short*)&h;
}

// ---------------------------------------------------------------------------
// K1: env_emb[n,h] = relu(env_features @ env_W + env_b)   (fp32, tiny)
// ---------------------------------------------------------------------------
__global__ __launch_bounds__(256) void env_kernel(
    const float* __restrict__ env_features,  // [N, E]
    const float* __restrict__ env_W,         // [E, H]
    const float* __restrict__ env_b,         // [H]
    float* __restrict__ env_emb)             // [N, H]
{
    int idx = blockIdx.x * 256 + threadIdx.x;
    int n = idx >> 6, h = idx & 63;
    float acc = env_b[h];
#pragma unroll
    for (int e = 0; e < E_; ++e)
        acc = fmaf(env_features[n * E_ + e], env_W[e * H_ + h], acc);
    env_emb[idx] = fmaxf(acc, 0.f);
}

// ---------------------------------------------------------------------------
// K2: src_bf/tgt_bf[p,n,h] = bf16(emb + env_emb[n,h])  for all 24 periods
// ---------------------------------------------------------------------------
__global__ __launch_bounds__(256) void srctgt_kernel(
    const float* __restrict__ src_emb, const float* __restrict__ tgt_emb,
    const float* __restrict__ env_emb,
    unsigned short* __restrict__ src_bf, unsigned short* __restrict__ tgt_bf)
{
    size_t idx = (size_t)blockIdx.x * 256 + threadIdx.x;   // < 24*65536
    float e = env_emb[idx & 65535u];
    src_bf[idx] = f2bf(src_emb[idx] + e);
    tgt_bf[idx] = f2bf(tgt_emb[idx] + e);
}

// ---------------------------------------------------------------------------
// K3: static_adj -> bf16 (values are exactly 0.0/1.0, conversion exact)
// ---------------------------------------------------------------------------
__global__ __launch_bounds__(256) void adjcvt_kernel(
    const float* __restrict__ adj, unsigned short* __restrict__ adj_bf)
{
    size_t i = ((size_t)blockIdx.x * 256 + threadIdx.x) * 4;
    float4 v = *(const float4*)(adj + i);
    ushort4 o;
    o.x = f2bf(v.x); o.y = f2bf(v.y); o.z = f2bf(v.z); o.w = f2bf(v.w);
    *(ushort4*)(adj_bf + i) = o;
}

// ---------------------------------------------------------------------------
// K4: Wt[f][d] = bf16(W[d][f]);  rWt likewise  (k-contiguous B operands)
// ---------------------------------------------------------------------------
__global__ __launch_bounds__(256) void wtrans_kernel(
    const float* __restrict__ W, const float* __restrict__ rW,
    unsigned short* __restrict__ Wt, unsigned short* __restrict__ rWt)
{
    int idx = blockIdx.x * 256 + threadIdx.x;   // 0..32767
    int which = idx >> 14, j = idx & 16383;
    int f = j >> 7, d = j & 127;
    if (which == 0) Wt[f * 128 + d]  = f2bf(W[d * 128 + f]);
    else            rWt[f * 128 + d] = f2bf(rW[d * 128 + f]);
}

// ---------------------------------------------------------------------------
// K5: support^T (swapped GEMM) + residual, both bf16 out, MFMA.
// Block = 32 rows of x (fp32 in, converted in-register).
// ---------------------------------------------------------------------------
__global__ __launch_bounds__(256) void gemm2_mfma(
    const float* __restrict__ x,               // [B*N][128] fp32
    const unsigned short* __restrict__ Wt,     // [128f][128d]
    const unsigned short* __restrict__ rWt,    // [128f][128d]
    const float* __restrict__ rb,              // [128]
    unsigned short* __restrict__ supT,         // [B][128f][1024m]
    unsigned short* __restrict__ resid)        // [B*N][128]
{
    const int t = threadIdx.x, w = t >> 6, l = t & 63;
    const int ln = l & 15, kb = l >> 4;
    const int mblk = w >> 1, fhalf = w & 1;
    const int row0 = blockIdx.x * 32;
    const int b   = row0 >> 10;
    const int mg0 = row0 & 1023;

    const float* xrow = x + (size_t)(row0 + mblk * 16 + ln) * 128;
    short8 xa[4];
#pragma unroll
    for (int k = 0; k < 4; ++k) {
        float4 v0 = *(const float4*)(xrow + k * 32 + kb * 8);
        float4 v1 = *(const float4*)(xrow + k * 32 + kb * 8 + 4);
        short8 s;
        s[0] = (short)f2bf(v0.x); s[1] = (short)f2bf(v0.y);
        s[2] = (short)f2bf(v0.z); s[3] = (short)f2bf(v0.w);
        s[4] = (short)f2bf(v1.x); s[5] = (short)f2bf(v1.y);
        s[6] = (short)f2bf(v1.z); s[7] = (short)f2bf(v1.w);
        xa[k] = s;
    }

    f32x4 accS[4], accR[4];
#pragma unroll
    for (int i = 0; i < 4; ++i) { accS[i] = (f32x4){0,0,0,0}; accR[i] = (f32x4){0,0,0,0}; }

#pragma unroll
    for (int k = 0; k < 4; ++k) {
#pragma unroll
        for (int fb = 0; fb < 4; ++fb) {
            int fr = (fhalf * 4 + fb) * 16 + ln;
            short8 wa = *(const short8*)(Wt  + (size_t)fr * 128 + k * 32 + kb * 8);
            short8 wb = *(const short8*)(rWt + (size_t)fr * 128 + k * 32 + kb * 8);
            accS[fb] = __builtin_amdgcn_mfma_f32_16x16x32_bf16(wa, xa[k], accS[fb], 0, 0, 0);
            accR[fb] = __builtin_amdgcn_mfma_f32_16x16x32_bf16(xa[k], wb, accR[fb], 0, 0, 0);
        }
    }

    // support^T: C[f][m]
#pragma unroll
    for (int fb = 0; fb < 4; ++fb) {
        int m = mg0 + mblk * 16 + ln;
#pragma unroll
        for (int i = 0; i < 4; ++i) {
            int f = (fhalf * 4 + fb) * 16 + kb * 4 + i;
            supT[((size_t)b * 128 + f) * 1024 + m] = f2bf(accS[fb][i]);
        }
    }
    // residual: C[m][f]
#pragma unroll
    for (int fb = 0; fb < 4; ++fb) {
        int f = (fhalf * 4 + fb) * 16 + ln;
        float rbf = rb[f];
#pragma unroll
        for (int i = 0; i < 4; ++i) {
            size_t row = (size_t)row0 + mblk * 16 + kb * 4 + i;
            resid[row * 128 + f] = f2bf(fmaxf(accR[fb][i] + rbf, 0.f));
        }
    }
}

// ---------------------------------------------------------------------------
// K6: fused scores -> relu*adj -> conv -> +bias +residual -> relu  (MFMA)
// Block = (b, 64-row n-tile), 8 waves / 512 threads.
// Score role: wave w -> n-tile sn=w&3, m-tile pair sm2=w>>2.
// Conv role:  wave w -> 32-row group cn=w&1, 32-col f group cf=w>>1.
// Double-buffered masked-A in LDS: iteration t scores chunk t+1 into buf^1
// while conv consumes buf (1 barrier/iter).
// ---------------------------------------------------------------------------
__global__ __launch_bounds__(512, 4) void conv_mfma(
    const unsigned short* __restrict__ src_bf,  // [P][N][64]
    const unsigned short* __restrict__ tgt_bf,  // [P][N][64]
    const unsigned short* __restrict__ adj_bf,  // [N][N]
    const unsigned short* __restrict__ supT,    // [B][128][1024]
    const unsigned short* __restrict__ resid,   // [B*N][128]
    const float* __restrict__ bias,             // [128]
    const int* __restrict__ cyc,                // [B]
    float* __restrict__ out)                    // [B][N][128]
{
    __shared__ unsigned short s_a[2][64][72] __attribute__((aligned(16)));

    const int b = blockIdx.y, n0 = blockIdx.x * 64;
    const int t = threadIdx.x, w = t >> 6, l = t & 63;
    const int ln = l & 15, kb = l >> 4;
    const int p = ((cyc[b] % NPER) + NPER) % NPER;

    const int sn = w & 3, sm2 = w >> 2;    // score role
    const int cn = w & 1, cf = w >> 1;     // conv role

    const unsigned short* srow = src_bf + ((size_t)p * N_ + n0 + sn * 16 + ln) * H_;
    const short8 sa0 = *(const short8*)(srow + kb * 8);
    const short8 sa1 = *(const short8*)(srow + 32 + kb * 8);

    const unsigned short* tbase = tgt_bf + (size_t)p * N_ * H_;
    const unsigned short* supb  = supT + (size_t)b * (size_t)F_ * N_;

    f32x4 acc[2][2];
#pragma unroll
    for (int r = 0; r < 2; ++r)
#pragma unroll
        for (int fb = 0; fb < 2; ++fb) acc[r][fb] = (f32x4){0, 0, 0, 0};

    auto score = [&](int m0, int wb) {
#pragma unroll
        for (int mt = 0; mt < 2; ++mt) {
            const int mtile = sm2 * 2 + mt;
            const unsigned short* trow = tbase + (size_t)(m0 + mtile * 16 + ln) * H_;
            short8 tb0 = *(const short8*)(trow + kb * 8);
            short8 tb1 = *(const short8*)(trow + 32 + kb * 8);
            f32x4 c = (f32x4){0, 0, 0, 0};
            c = __builtin_amdgcn_mfma_f32_16x16x32_bf16(sa0, tb0, c, 0, 0, 0);
            c = __builtin_amdgcn_mfma_f32_16x16x32_bf16(sa1, tb1, c, 0, 0, 0);
            const int ml = mtile * 16 + ln;
#pragma unroll
            for (int i = 0; i < 4; ++i) {
                const int nl = sn * 16 + kb * 4 + i;
                float av = fmaxf(c[i], 0.f)
                         * bf2f(adj_bf[(size_t)(n0 + nl) * N_ + m0 + ml]);
                s_a[wb][nl][ml] = f2bf_hw(av);
            }
        }
    };

    auto conv = [&](int m0, int rb) {
#pragma unroll
        for (int ks = 0; ks < 2; ++ks) {
            short8 af[2];
#pragma unroll
            for (int r = 0; r < 2; ++r)
                af[r] = *(const short8*)(&s_a[rb][cn * 32 + r * 16 + ln][ks * 32 + kb * 8]);
#pragma unroll
            for (int fb = 0; fb < 2; ++fb) {
                const int f = cf * 32 + fb * 16 + ln;
                short8 bs = *(const short8*)(supb + (size_t)f * N_ + m0 + ks * 32 + kb * 8);
                acc[0][fb] = __builtin_amdgcn_mfma_f32_16x16x32_bf16(af[0], bs, acc[0][fb], 0, 0, 0);
                acc[1][fb] = __builtin_amdgcn_mfma_f32_16x16x32_bf16(af[1], bs, acc[1][fb], 0, 0, 0);
            }
        }
    };

    score(0, 0);
    __syncthreads();

    for (int tt = 0; tt < 16; tt += 2) {
        // sub-iter A: read buf0, write buf1
        score((tt + 1) * 64, 1);
        conv(tt * 64, 0);
        __syncthreads();
        // sub-iter B: read buf1, write buf0
        if (tt + 2 < 16) score((tt + 2) * 64, 0);
        conv((tt + 1) * 64, 1);
        __syncthreads();
    }

    // epilogue: out = relu(conv + bias + residual)
#pragma unroll
    for (int r = 0; r < 2; ++r)
#pragma unroll
    for (int fb = 0; fb < 2; ++fb) {
        const int f = cf * 32 + fb * 16 + ln;
        const float bi = bias[f];
#pragma unroll
        for (int i = 0; i < 4; ++i) {
            const int n = n0 + cn * 32 + r * 16 + kb * 4 + i;
            const size_t o = ((size_t)b * N_ + n) * F_ + f;
            out[o] = fmaxf(acc[r][fb][i] + bi + bf2f(resid[o]), 0.f);
        }
    }
}

// ---------------------------------------------------------------------------
extern "C" void kernel_launch(void* const* d_in, const int* in_sizes, int n_in,
                              void* d_out, int out_size, void* d_ws, size_t ws_size,
                              hipStream_t stream) {
    const float* input_features = (const float*)d_in[0];
    const int*   cycle_indices  = (const int*)  d_in[1];
    const float* weight         = (const float*)d_in[2];
    const float* bias           = (const float*)d_in[3];
    const float* src_emb        = (const float*)d_in[4];
    const float* tgt_emb        = (const float*)d_in[5];
    const float* env_W          = (const float*)d_in[6];
    const float* env_b          = (const float*)d_in[7];
    const float* res_W          = (const float*)d_in[8];
    const float* res_b          = (const float*)d_in[9];
    const float* static_adj     = (const float*)d_in[10];
    const float* env_features   = (const float*)d_in[11];
    float* out = (float*)d_out;

    // workspace layout (~24.3 MiB)
    char* wsb = (char*)d_ws;
    float*          env_emb = (float*)wsb;                        // 262144 B
    unsigned short* src_bf  = (unsigned short*)(wsb + 262144);    // 3145728 B
    unsigned short* tgt_bf  = src_bf + (size_t)NPER * N_ * H_;    // 3145728 B
    unsigned short* Wt      = tgt_bf + (size_t)NPER * N_ * H_;    // 32768 B
    unsigned short* rWt     = Wt + 16384;                         // 32768 B
    unsigned short* supT    = rWt + 16384;                        // 8388608 B
    unsigned short* resid   = supT + (size_t)B_ * F_ * N_;        // 8388608 B
    unsigned short* adj_bf  = resid + (size_t)B_ * N_ * F_;       // 2097152 B

    env_kernel<<<(N_ * H_) / 256, 256, 0, stream>>>(env_features, env_W, env_b, env_emb);

    srctgt_kernel<<<(NPER * N_ * H_) / 256, 256, 0, stream>>>(
        src_emb, tgt_emb, env_emb, src_bf, tgt_bf);

    adjcvt_kernel<<<(N_ * N_) / (4 * 256), 256, 0, stream>>>(static_adj, adj_bf);

    wtrans_kernel<<<(2 * F_ * F_) / 256, 256, 0, stream>>>(weight, res_W, Wt, rWt);

    gemm2_mfma<<<(B_ * N_) / 32, 256, 0, stream>>>(
        input_features, Wt, rWt, res_b, supT, resid);

    dim3 grid(N_ / 64, B_);
    conv_mfma<<<grid, 512, 0, stream>>>(
        src_bf, tgt_bf, adj_bf, supT, resid, bias, cycle_indices, out);
}

// Round 4
// 99.642 us; speedup vs baseline: 15.2742x; 1.0629x over previous
//
#include <hip/hip_runtime.h>
#include <hip/hip_bf16.h>

#define NPER 24
#define B_ 32
#define N_ 1024
#define F_ 128
#define H_ 64
#define E_ 16

typedef __attribute__((ext_vector_type(8))) short short8;
typedef __attribute__((ext_vector_type(4))) float f32x4;

static __device__ __forceinline__ unsigned short f2bf(float x) {
    union { float f; unsigned u; } v; v.f = x;
    unsigned r = v.u + 0x7fffu + ((v.u >> 16) & 1u);   // RNE
    return (unsigned short)(r >> 16);
}
static __device__ __forceinline__ float bf2f(unsigned short h) {
    union { unsigned u; float f; } v; v.u = ((unsigned)h) << 16; return v.f;
}
static __device__ __forceinline__ unsigned short f2bf_hw(float x) {
    __hip_bfloat16 h = __float2bfloat16(x);
    return *(unsigned short*)&h;
}

// ---------------------------------------------------------------------------
// P1: env encoder fused into src/tgt bf16 conversion for all 24 periods.
// One thread per (n,h); env recomputed in-register (16 FMA), then 24 passes.
// ---------------------------------------------------------------------------
__global__ __launch_bounds__(256) void prep_srctgt(
    const float* __restrict__ src_emb, const float* __restrict__ tgt_emb,
    const float* __restrict__ env_features, const float* __restrict__ env_W,
    const float* __restrict__ env_b,
    unsigned short* __restrict__ src_bf, unsigned short* __restrict__ tgt_bf)
{
    const int idx = blockIdx.x * 256 + threadIdx.x;   // 0..65535
    const int n = idx >> 6, h = idx & 63;
    float e = env_b[h];
#pragma unroll
    for (int k = 0; k < E_; ++k)
        e = fmaf(env_features[n * E_ + k], env_W[k * H_ + h], e);
    e = fmaxf(e, 0.f);
#pragma unroll 4
    for (int p = 0; p < NPER; ++p) {
        const size_t off = (size_t)p * (N_ * H_) + idx;
        src_bf[off] = f2bf(src_emb[off] + e);
        tgt_bf[off] = f2bf(tgt_emb[off] + e);
    }
}

// ---------------------------------------------------------------------------
// P2: adj -> bf16 (blocks 0..1023) ; W/rW transpose -> bf16 (blocks 1024..1151)
// ---------------------------------------------------------------------------
__global__ __launch_bounds__(256) void prep_cvt(
    const float* __restrict__ adj, const float* __restrict__ W,
    const float* __restrict__ rW,
    unsigned short* __restrict__ adj_bf, unsigned short* __restrict__ Wt,
    unsigned short* __restrict__ rWt)
{
    const int bid = blockIdx.x;
    if (bid < 1024) {
        const size_t i = ((size_t)bid * 256 + threadIdx.x) * 4;
        float4 v = *(const float4*)(adj + i);
        ushort4 o;
        o.x = f2bf(v.x); o.y = f2bf(v.y); o.z = f2bf(v.z); o.w = f2bf(v.w);
        *(ushort4*)(adj_bf + i) = o;
    } else {
        const int idx = (bid - 1024) * 256 + threadIdx.x;   // 0..32767
        const int which = idx >> 14, j = idx & 16383;
        const int f = j >> 7, d = j & 127;
        if (which == 0) Wt[f * 128 + d]  = f2bf(W[d * 128 + f]);
        else            rWt[f * 128 + d] = f2bf(rW[d * 128 + f]);
    }
}

// ---------------------------------------------------------------------------
// K5: support^T (swapped GEMM) + residual, both bf16 out, MFMA.
// Block = 32 rows of x (fp32 in, converted in-register).  [verified r2/r3]
// ---------------------------------------------------------------------------
__global__ __launch_bounds__(256) void gemm2_mfma(
    const float* __restrict__ x,               // [B*N][128] fp32
    const unsigned short* __restrict__ Wt,     // [128f][128d]
    const unsigned short* __restrict__ rWt,    // [128f][128d]
    const float* __restrict__ rb,              // [128]
    unsigned short* __restrict__ supT,         // [B][128f][1024m]
    unsigned short* __restrict__ resid)        // [B*N][128]
{
    const int t = threadIdx.x, w = t >> 6, l = t & 63;
    const int ln = l & 15, kb = l >> 4;
    const int mblk = w >> 1, fhalf = w & 1;
    const int row0 = blockIdx.x * 32;
    const int b   = row0 >> 10;
    const int mg0 = row0 & 1023;

    const float* xrow = x + (size_t)(row0 + mblk * 16 + ln) * 128;
    short8 xa[4];
#pragma unroll
    for (int k = 0; k < 4; ++k) {
        float4 v0 = *(const float4*)(xrow + k * 32 + kb * 8);
        float4 v1 = *(const float4*)(xrow + k * 32 + kb * 8 + 4);
        short8 s;
        s[0] = (short)f2bf(v0.x); s[1] = (short)f2bf(v0.y);
        s[2] = (short)f2bf(v0.z); s[3] = (short)f2bf(v0.w);
        s[4] = (short)f2bf(v1.x); s[5] = (short)f2bf(v1.y);
        s[6] = (short)f2bf(v1.z); s[7] = (short)f2bf(v1.w);
        xa[k] = s;
    }

    f32x4 accS[4], accR[4];
#pragma unroll
    for (int i = 0; i < 4; ++i) { accS[i] = (f32x4){0,0,0,0}; accR[i] = (f32x4){0,0,0,0}; }

#pragma unroll
    for (int k = 0; k < 4; ++k) {
#pragma unroll
        for (int fb = 0; fb < 4; ++fb) {
            int fr = (fhalf * 4 + fb) * 16 + ln;
            short8 wa = *(const short8*)(Wt  + (size_t)fr * 128 + k * 32 + kb * 8);
            short8 wb = *(const short8*)(rWt + (size_t)fr * 128 + k * 32 + kb * 8);
            accS[fb] = __builtin_amdgcn_mfma_f32_16x16x32_bf16(wa, xa[k], accS[fb], 0, 0, 0);
            accR[fb] = __builtin_amdgcn_mfma_f32_16x16x32_bf16(xa[k], wb, accR[fb], 0, 0, 0);
        }
    }

    // support^T: C[f][m]
#pragma unroll
    for (int fb = 0; fb < 4; ++fb) {
        int m = mg0 + mblk * 16 + ln;
#pragma unroll
        for (int i = 0; i < 4; ++i) {
            int f = (fhalf * 4 + fb) * 16 + kb * 4 + i;
            supT[((size_t)b * 128 + f) * 1024 + m] = f2bf(accS[fb][i]);
        }
    }
    // residual: C[m][f]
#pragma unroll
    for (int fb = 0; fb < 4; ++fb) {
        int f = (fhalf * 4 + fb) * 16 + ln;
        float rbf = rb[f];
#pragma unroll
        for (int i = 0; i < 4; ++i) {
            size_t row = (size_t)row0 + mblk * 16 + kb * 4 + i;
            resid[row * 128 + f] = f2bf(fmaxf(accR[fb][i] + rbf, 0.f));
        }
    }
}

// ---------------------------------------------------------------------------
// K6: fused scores -> relu*adj -> conv -> +bias +residual -> relu  (MFMA)
// Block = 32 n-rows, 256 threads / 4 waves, grid 1024 (chunked XCD swizzle).
// All global operands (tgt, adj, supT) register-prefetched one 64-m chunk
// ahead; masked-A double-buffered in LDS; 1 barrier per chunk.
// Score role: wave w -> n-tile sn=w>>1, m-pair sm=w&1.
// Conv role:  wave w -> 32-col f group cf=w.
// ---------------------------------------------------------------------------
__global__ __launch_bounds__(256, 4) void conv_mfma(
    const unsigned short* __restrict__ src_bf,  // [P][N][64]
    const unsigned short* __restrict__ tgt_bf,  // [P][N][64]
    const unsigned short* __restrict__ adj_bf,  // [N][N]
    const unsigned short* __restrict__ supT,    // [B][128][1024]
    const unsigned short* __restrict__ resid,   // [B*N][128]
    const float* __restrict__ bias,             // [128]
    const int* __restrict__ cyc,                // [B]
    float* __restrict__ out)                    // [B][N][128]
{
    __shared__ unsigned short s_a[2][32][72] __attribute__((aligned(16)));

    // chunked XCD swizzle: dispatch id i -> XCD i%8; XCD k gets works
    // [k*128, (k+1)*128) = 4 consecutive b's (supT/tgt slice fits 4MB L2).
    const int i = blockIdx.x;                    // 0..1023
    const int work = (i & 7) * 128 + (i >> 3);
    const int b  = work >> 5;
    const int n0 = (work & 31) * 32;

    const int t = threadIdx.x, w = t >> 6, l = t & 63;
    const int ln = l & 15, kb = l >> 4;
    const int p = ((cyc[b] % NPER) + NPER) % NPER;

    const int sn = w >> 1, sm = w & 1;   // score role
    const int cf = w;                     // conv role

    const unsigned short* srow = src_bf + ((size_t)p * N_ + n0 + sn * 16 + ln) * H_;
    const short8 sa0 = *(const short8*)(srow + kb * 8);
    const short8 sa1 = *(const short8*)(srow + 32 + kb * 8);

    const unsigned short* tbase = tgt_bf + (size_t)p * N_ * H_;
    const unsigned short* supb  = supT + (size_t)b * (size_t)F_ * N_;

    f32x4 acc[2][2];
#pragma unroll
    for (int r = 0; r < 2; ++r)
#pragma unroll
        for (int fb = 0; fb < 2; ++fb) acc[r][fb] = (f32x4){0, 0, 0, 0};

    auto loadT = [&](int m0, short8 (&tb)[2][2], unsigned short (&av)[2][4]) {
#pragma unroll
        for (int mt = 0; mt < 2; ++mt) {
            const unsigned short* trow =
                tbase + (size_t)(m0 + (sm * 2 + mt) * 16 + ln) * H_;
            tb[mt][0] = *(const short8*)(trow + kb * 8);
            tb[mt][1] = *(const short8*)(trow + 32 + kb * 8);
            const int ml = (sm * 2 + mt) * 16 + ln;
#pragma unroll
            for (int ii = 0; ii < 4; ++ii)
                av[mt][ii] = adj_bf[(size_t)(n0 + sn * 16 + kb * 4 + ii) * N_ + m0 + ml];
        }
    };
    auto loadS = [&](int m0, short8 (&bs)[2][2]) {
#pragma unroll
        for (int ks = 0; ks < 2; ++ks)
#pragma unroll
            for (int fb = 0; fb < 2; ++fb)
                bs[ks][fb] = *(const short8*)(
                    supb + (size_t)(cf * 32 + fb * 16 + ln) * N_ + m0 + ks * 32 + kb * 8);
    };
    auto score = [&](const short8 (&tb)[2][2], const unsigned short (&av)[2][4], int wb) {
#pragma unroll
        for (int mt = 0; mt < 2; ++mt) {
            f32x4 c = (f32x4){0, 0, 0, 0};
            c = __builtin_amdgcn_mfma_f32_16x16x32_bf16(sa0, tb[mt][0], c, 0, 0, 0);
            c = __builtin_amdgcn_mfma_f32_16x16x32_bf16(sa1, tb[mt][1], c, 0, 0, 0);
            const int ml = (sm * 2 + mt) * 16 + ln;
#pragma unroll
            for (int ii = 0; ii < 4; ++ii) {
                float a2 = fmaxf(c[ii], 0.f) * bf2f(av[mt][ii]);
                s_a[wb][sn * 16 + kb * 4 + ii][ml] = f2bf_hw(a2);
            }
        }
    };
    auto conv = [&](int rb, const short8 (&bs)[2][2]) {
#pragma unroll
        for (int ks = 0; ks < 2; ++ks) {
            short8 af0 = *(const short8*)(&s_a[rb][ln][ks * 32 + kb * 8]);
            short8 af1 = *(const short8*)(&s_a[rb][16 + ln][ks * 32 + kb * 8]);
#pragma unroll
            for (int fb = 0; fb < 2; ++fb) {
                acc[0][fb] = __builtin_amdgcn_mfma_f32_16x16x32_bf16(af0, bs[ks][fb], acc[0][fb], 0, 0, 0);
                acc[1][fb] = __builtin_amdgcn_mfma_f32_16x16x32_bf16(af1, bs[ks][fb], acc[1][fb], 0, 0, 0);
            }
        }
    };

    short8 tbA[2][2], tbB[2][2];
    unsigned short adjA[2][4], adjB[2][4];
    short8 bsA[2][2], bsB[2][2];

    // prologue: T[0], S[0], T[1]; score chunk 0 -> buf0
    loadT(0, tbA, adjA);
    loadS(0, bsA);
    loadT(64, tbB, adjB);
    score(tbA, adjA, 0);
    __syncthreads();

#pragma unroll
    for (int tt = 0; tt < 16; tt += 2) {
        // iter tt: conv chunk tt (bsA, buf0); score chunk tt+1 (tbB -> buf1)
        loadS((tt + 1) * 64, bsB);
        if (tt + 2 < 16) loadT((tt + 2) * 64, tbA, adjA);
        conv(0, bsA);
        score(tbB, adjB, 1);
        __syncthreads();

        // iter tt+1: conv chunk tt+1 (bsB, buf1); score chunk tt+2 (tbA -> buf0)
        if (tt + 2 < 16) loadS((tt + 2) * 64, bsA);
        if (tt + 3 < 16) loadT((tt + 3) * 64, tbB, adjB);
        conv(1, bsB);
        if (tt + 2 < 16) score(tbA, adjA, 0);
        __syncthreads();
    }

    // epilogue: out = relu(conv + bias + residual)
#pragma unroll
    for (int r = 0; r < 2; ++r)
#pragma unroll
    for (int fb = 0; fb < 2; ++fb) {
        const int f = cf * 32 + fb * 16 + ln;
        const float bi = bias[f];
#pragma unroll
        for (int ii = 0; ii < 4; ++ii) {
            const int n = n0 + r * 16 + kb * 4 + ii;
            const size_t o = ((size_t)b * N_ + n) * F_ + f;
            out[o] = fmaxf(acc[r][fb][ii] + bi + bf2f(resid[o]), 0.f);
        }
    }
}

// ---------------------------------------------------------------------------
extern "C" void kernel_launch(void* const* d_in, const int* in_sizes, int n_in,
                              void* d_out, int out_size, void* d_ws, size_t ws_size,
                              hipStream_t stream) {
    const float* input_features = (const float*)d_in[0];
    const int*   cycle_indices  = (const int*)  d_in[1];
    const float* weight         = (const float*)d_in[2];
    const float* bias           = (const float*)d_in[3];
    const float* src_emb        = (const float*)d_in[4];
    const float* tgt_emb        = (const float*)d_in[5];
    const float* env_W          = (const float*)d_in[6];
    const float* env_b          = (const float*)d_in[7];
    const float* res_W          = (const float*)d_in[8];
    const float* res_b          = (const float*)d_in[9];
    const float* static_adj     = (const float*)d_in[10];
    const float* env_features   = (const float*)d_in[11];
    float* out = (float*)d_out;

    // workspace layout (~25.2 MiB)
    char* wsb = (char*)d_ws;
    unsigned short* src_bf = (unsigned short*)wsb;               // 3145728 B
    unsigned short* tgt_bf = src_bf + (size_t)NPER * N_ * H_;    // 3145728 B
    unsigned short* Wt     = tgt_bf + (size_t)NPER * N_ * H_;    // 32768 B
    unsigned short* rWt    = Wt + 16384;                         // 32768 B
    unsigned short* supT   = rWt + 16384;                        // 8388608 B
    unsigned short* resid  = supT + (size_t)B_ * F_ * N_;        // 8388608 B
    unsigned short* adj_bf = resid + (size_t)B_ * N_ * F_;       // 2097152 B

    prep_srctgt<<<(N_ * H_) / 256, 256, 0, stream>>>(
        src_emb, tgt_emb, env_features, env_W, env_b, src_bf, tgt_bf);

    prep_cvt<<<1024 + 128, 256, 0, stream>>>(
        static_adj, weight, res_W, adj_bf, Wt, rWt);

    gemm2_mfma<<<(B_ * N_) / 32, 256, 0, stream>>>(
        input_features, Wt, rWt, res_b, supT, resid);

    conv_mfma<<<1024, 256, 0, stream>>>(
        src_bf, tgt_bf, adj_bf, supT, resid, bias, cycle_indices, out);
}